// Round 7
// baseline (133.492 us; speedup 1.0000x reference)
//
#include <hip/hip_runtime.h>
#include <hip/hip_bf16.h>
#include <math.h>

#define C    32      // attention dim
#define QD   64      // x1 channels
#define VD   64      // output channels
#define BLK  512     // sliding window block length
#define HALF 256

typedef __attribute__((ext_vector_type(8))) short bf16x8;
typedef __attribute__((ext_vector_type(4))) float f32x4;

static __device__ inline unsigned short f2bf(float x) {
    union { float f; unsigned u; } v; v.f = x;
    unsigned r = v.u + 0x7FFFu + ((v.u >> 16) & 1u);   // RNE
    return (unsigned short)(r >> 16);
}

// pack 2 floats -> one dword holding 2 bf16 (low = a, high = b)
static __device__ inline unsigned pk2(float a, float b) {
    union { __hip_bfloat162 h; unsigned u; } x;
    x.h = __float22bfloat162_rn(make_float2(a, b));
    return x.u;
}

// ---------------- kernel 1: QKV projection via MFMA + LDS-staged stores ----
// qkv history: R1 fused-96-acc spill (VGPR cap 60); R3 runtime-kind loop
// broke SROA (VGPR 32, scratch); R5 MFMA rewrite 38->23us; R6 LDS-staged
// coalesced stores NEUTRAL (~22.6us) -> qkv is NOT store-bound, NOT
// VALU-bound (~1.3us model), NOT HBM-bound (29MB ~ 4.6us). Remaining gap
// unexplained after 2 targeted fixes; parked. Layouts for att_kernel:
//   qT bf16 (L,32) pre-scaled; kT bf16 (L,32);
//   v2 bf16 tiled: idx = ((l>>6)<<11) + (((l>>5)&1)<<10) + ch*32 + (l&31)
__global__ __launch_bounds__(256) void qkv_proj(
    const float* __restrict__ x1,
    const float* __restrict__ Wq, const float* __restrict__ bq,
    const float* __restrict__ Wk, const float* __restrict__ bk,
    const float* __restrict__ Wv, const float* __restrict__ bv,
    unsigned short* __restrict__ qT, unsigned short* __restrict__ kT,
    unsigned short* __restrict__ v2, int L)
{
    __shared__ uint4 lq[256], lk[256], lv[256];   // 3 x 4KB

    const int lane = threadIdx.x & 63;
    const int wv   = threadIdx.x >> 6;
    const int lo   = lane & 15;
    const int quad = lane >> 4;

    const int tile = blockIdx.x * 4 + wv;   // one 16-l tile per wave
    const int l    = tile * 16 + lo;
    const int ll   = wv * 16 + lo;          // l offset within the wg's 64-l block

    // ---- B-frags: x1 in bf16. lane(lo,quad) holds x1[c=kc*32+quad*8+j][l]
    float xv[16];
    #pragma unroll
    for (int kc = 0; kc < 2; ++kc)
        #pragma unroll
        for (int j = 0; j < 8; ++j)
            xv[kc * 8 + j] = x1[(size_t)(kc * 32 + quad * 8 + j) * L + l];

    bf16x8 B[2];
    #pragma unroll
    for (int kc = 0; kc < 2; ++kc) {
        union { unsigned u[4]; bf16x8 v; } bb;
        #pragma unroll
        for (int p = 0; p < 4; ++p)
            bb.u[p] = pk2(xv[kc * 8 + 2 * p], xv[kc * 8 + 2 * p + 1]);
        B[kc] = bb.v;
    }

    // ---- A-frags: W in bf16. lane(lo,quad) = W[o=ot*16+lo][c=kc*32+quad*8+j]
    bf16x8 A[3][2][2];  // [kind][otile][kchunk] — static indices after unroll
    #pragma unroll
    for (int kind = 0; kind < 3; ++kind) {
        const float* __restrict__ Wp = (kind == 0) ? Wq : ((kind == 1) ? Wk : Wv);
        const float sc = (kind == 0) ? 0.17677669529663689f : 1.0f;
        #pragma unroll
        for (int ot = 0; ot < 2; ++ot) {
            #pragma unroll
            for (int kc = 0; kc < 2; ++kc) {
                const float* wp = Wp + (size_t)(ot * 16 + lo) * QD + kc * 32 + quad * 8;
                const float4 w0 = *(const float4*)wp;
                const float4 w1 = *(const float4*)(wp + 4);
                union { unsigned u[4]; bf16x8 v; } t;
                t.u[0] = pk2(w0.x * sc, w0.y * sc);
                t.u[1] = pk2(w0.z * sc, w0.w * sc);
                t.u[2] = pk2(w1.x * sc, w1.y * sc);
                t.u[3] = pk2(w1.z * sc, w1.w * sc);
                A[kind][ot][kc] = t.v;
            }
        }
    }

    // ---- 12 MFMAs: acc[kind][ot] over 2 k-chunks.
    // C/D layout: lane(lo,quad) reg r = O[o = ot*16 + quad*4 + r][l]
    const f32x4 zero = {0.f, 0.f, 0.f, 0.f};
    f32x4 acc[3][2];
    #pragma unroll
    for (int kind = 0; kind < 3; ++kind)
        #pragma unroll
        for (int ot = 0; ot < 2; ++ot) {
            f32x4 a = __builtin_amdgcn_mfma_f32_16x16x32_bf16(A[kind][ot][0], B[0], zero, 0, 0, 0);
            acc[kind][ot] = __builtin_amdgcn_mfma_f32_16x16x32_bf16(A[kind][ot][1], B[1], a, 0, 0, 0);
        }

    // ---- stage bias+pack into LDS ----
    #pragma unroll
    for (int kind = 0; kind < 2; ++kind) {
        const float* __restrict__ bp = (kind == 0) ? bq : bk;
        const float sc = (kind == 0) ? 0.17677669529663689f : 1.0f;
        unsigned* __restrict__ ld = (unsigned*)((kind == 0) ? lq : lk);
        #pragma unroll
        for (int ot = 0; ot < 2; ++ot) {
            const float4 b4 = *(const float4*)(bp + ot * 16 + quad * 4);
            const float r0 = acc[kind][ot][0] + b4.x * sc;
            const float r1 = acc[kind][ot][1] + b4.y * sc;
            const float r2 = acc[kind][ot][2] + b4.z * sc;
            const float r3 = acc[kind][ot][3] + b4.w * sc;
            ld[ll * 16 + ot * 8 + quad * 2 + 0] = pk2(r0, r1);
            ld[ll * 16 + ot * 8 + quad * 2 + 1] = pk2(r2, r3);
        }
    }
    // v: tiled [ll>=32][ch][ll&31] shorts
    {
        unsigned short* __restrict__ lvs = (unsigned short*)lv;
        const int vb = ((ll >> 5) << 10) + (ll & 31);
        #pragma unroll
        for (int ot = 0; ot < 2; ++ot) {
            const float4 b4 = *(const float4*)(bv + ot * 16 + quad * 4);
            const float* bp4 = (const float*)&b4;
            #pragma unroll
            for (int r = 0; r < 4; ++r)
                lvs[vb + (ot * 16 + quad * 4 + r) * 32] = f2bf(acc[2][ot][r] + bp4[r]);
        }
    }

    __syncthreads();

    // ---- coalesced write-out: each thread 3x uint4 ----
    const int t = threadIdx.x;
    const size_t blk16 = (size_t)blockIdx.x * 256;   // uint4 index of this wg's 4KB block
    ((uint4*)qT)[blk16 + t] = lq[t];
    ((uint4*)kT)[blk16 + t] = lk[t];
    ((uint4*)v2)[blk16 + t] = lv[t];
}

// ---------------- kernel 2: MFMA flash attention, split-K waves ----------
// wg = 128 thr = 2 waves covering the SAME 16 queries, alternate 64-key
// chunks (deferred-sum softmax is order-independent). LPT dispatch order,
// XCD-affine. Exactly one causal chunk per tile.
// Grid MUST be L/16 wgs (one per 16-query tile).
// R7: software-pipelined chunk loop — prefetch chunk j+2's K+mask before
// processing chunk j; current chunk's V loads issued right after S-MFMAs
// (exp/shfl ~400cy covers their L2 latency). Wo/bo/mk loads hoisted before
// the merge barrier. launch_bounds (128,3): pipelining holds ~48 more live
// VGPRs (kN/fmN/vA); a 128-cap at min-waves=4 would spill (R1 lesson);
// R4 showed 8->4 waves neutral so 4->3 should cost little.
__global__ __launch_bounds__(128, 3) void att_kernel(
    const unsigned short* __restrict__ qT,
    const unsigned short* __restrict__ kT,
    const unsigned short* __restrict__ v2,
    const float* __restrict__ mask,
    const float* __restrict__ Wo, const float* __restrict__ bo,
    float* __restrict__ out, int L)
{
    __shared__ float mrg[64 * 9];

    const int tid  = threadIdx.x;
    const int lane = tid & 63;
    const int h    = tid >> 6;          // wave parity within pair
    const int lo   = lane & 15;
    const int quad = lane >> 4;

    // LPT + XCD affinity: id = (31-s)*128 + w  ->  long waves first, id%8==w%8
    const int id = blockIdx.x;
    const int w  = id & 127;
    const int s  = 31 - (id >> 7);
    const int wq0 = w * BLK + s * 16;

    const int kstart = max(0, w * BLK - HALF);
    const int n      = ((wq0 + 15 - kstart) >> 6) + 1;   // total 64-key chunks
    const int myq    = wq0 + lo;

    // Q B-frag: B[k=c][n=q]
    const bf16x8 qB = *(const bf16x8*)(qT + (size_t)myq * C + quad * 8);

    const f32x4 zero = {0.f, 0.f, 0.f, 0.f};
    f32x4 O0 = zero, O1 = zero;
    float psum = 0.f;

    const int qsl = lo + 16 * ((quad & 1) << 1);

    // ---- prologue: preload first full chunk's K + mask (safe even if the
    // loop never runs: kb0+127 < L for every tile) ----
    bf16x8 kA[4]; float4 fm4[4];
    {
        const int kb0 = kstart + (h << 6);
        const unsigned short* kp = kT + (size_t)(kb0 + lo) * C + quad * 8;
        #pragma unroll
        for (int t = 0; t < 4; ++t) {
            kA[t]  = *(const bf16x8*)(kp + (size_t)(t * 16) * C);
            fm4[t] = *(const float4*)(mask + kb0 + t * 16 + quad * 4);
        }
    }

    // ---- full chunks (no causal masking), pipelined ----
    for (int j = h; j < n - 1; j += 2) {
        const int kb = kstart + (j << 6);

        // S-MFMAs on the preloaded K-frags
        f32x4 S[4];
        #pragma unroll
        for (int t = 0; t < 4; ++t)
            S[t] = __builtin_amdgcn_mfma_f32_16x16x32_bf16(kA[t], qB, zero, 0, 0, 0);

        // issue current-chunk V loads (consumed after exp/shfl) ...
        const unsigned short* vbase = v2 + ((size_t)(kb >> 6) << 11);
        bf16x8 vA[4];
        #pragma unroll
        for (int g = 0; g < 2; ++g) {
            vA[2 * g + 0] = *(const bf16x8*)(vbase + g * 1024 + lo * 32 + quad * 8);
            vA[2 * g + 1] = *(const bf16x8*)(vbase + g * 1024 + (16 + lo) * 32 + quad * 8);
        }
        // ... and next-chunk K + mask (reload current when no next: harmless)
        const int jn  = j + 2;
        const int kbn = kstart + ((jn < n - 1 ? jn : j) << 6);
        bf16x8 kN[4]; float4 fmN[4];
        {
            const unsigned short* kpn = kT + (size_t)(kbn + lo) * C + quad * 8;
            #pragma unroll
            for (int t = 0; t < 4; ++t) {
                kN[t]  = *(const bf16x8*)(kpn + (size_t)(t * 16) * C);
                fmN[t] = *(const float4*)(mask + kbn + t * 16 + quad * 4);
            }
        }

        // softmax numerators (covers the in-flight loads)
        unsigned wp[4][2];
        #pragma unroll
        for (int t = 0; t < 4; ++t) {
            const float* fmp = (const float*)&fm4[t];
            float p[4];
            #pragma unroll
            for (int r = 0; r < 4; ++r) {
                const float pd = __expf(S[t][r]) * (fmp[r] + 1e-9f);
                psum += pd;
                p[r] = pd * fmp[r];
            }
            wp[t][0] = pk2(p[0], p[1]);
            wp[t][1] = pk2(p[2], p[3]);
        }

        // PV on current chunk
        #pragma unroll
        for (int g = 0; g < 2; ++g) {
            union { int i[4]; bf16x8 v; } pb;
            #pragma unroll
            for (int i = 0; i < 4; ++i) {
                const int src = qsl + 16 * (i >> 1);
                const int v0 = __shfl((int)wp[2 * g][i & 1], src);
                const int v1 = __shfl((int)wp[2 * g + 1][i & 1], src);
                pb.i[i] = (quad < 2) ? v0 : v1;
            }
            O0 = __builtin_amdgcn_mfma_f32_16x16x32_bf16(vA[2 * g + 0], pb.v, O0, 0, 0, 0);
            O1 = __builtin_amdgcn_mfma_f32_16x16x32_bf16(vA[2 * g + 1], pb.v, O1, 0, 0, 0);
        }

        // rotate prefetched K/mask into place
        #pragma unroll
        for (int t = 0; t < 4; ++t) { kA[t] = kN[t]; fm4[t] = fmN[t]; }
    }

    // ---- the single causal chunk (owner: parity of n-1) ----
    if (((n - 1) & 1) == h) {
        const int kb = kstart + ((n - 1) << 6);

        f32x4 S[4];
        float4 fc4[4];
        const unsigned short* kp = kT + (size_t)(kb + lo) * C + quad * 8;
        #pragma unroll
        for (int t = 0; t < 4; ++t) {
            const bf16x8 kC = *(const bf16x8*)(kp + (size_t)(t * 16) * C);
            S[t] = __builtin_amdgcn_mfma_f32_16x16x32_bf16(kC, qB, zero, 0, 0, 0);
            fc4[t] = *(const float4*)(mask + kb + t * 16 + quad * 4);
        }

        unsigned wp[4][2];
        #pragma unroll
        for (int t = 0; t < 4; ++t) {
            const float* fmp = (const float*)&fc4[t];
            float p[4];
            #pragma unroll
            for (int r = 0; r < 4; ++r) {
                const int key = kb + t * 16 + quad * 4 + r;
                const float pd = (key <= myq) ? __expf(S[t][r]) * (fmp[r] + 1e-9f) : 0.f;
                psum += pd;
                p[r] = pd * fmp[r];
            }
            wp[t][0] = pk2(p[0], p[1]);
            wp[t][1] = pk2(p[2], p[3]);
        }

        const unsigned short* vbase = v2 + ((size_t)(kb >> 6) << 11);
        #pragma unroll
        for (int g = 0; g < 2; ++g) {
            union { int i[4]; bf16x8 v; } pb;
            #pragma unroll
            for (int i = 0; i < 4; ++i) {
                const int src = qsl + 16 * (i >> 1);
                const int v0 = __shfl((int)wp[2 * g][i & 1], src);
                const int v1 = __shfl((int)wp[2 * g + 1][i & 1], src);
                pb.i[i] = (quad < 2) ? v0 : v1;
            }
            const bf16x8 vA0 = *(const bf16x8*)(vbase + g * 1024 + lo * 32 + quad * 8);
            const bf16x8 vA1 = *(const bf16x8*)(vbase + g * 1024 + (16 + lo) * 32 + quad * 8);
            O0 = __builtin_amdgcn_mfma_f32_16x16x32_bf16(vA0, pb.v, O0, 0, 0, 0);
            O1 = __builtin_amdgcn_mfma_f32_16x16x32_bf16(vA1, pb.v, O1, 0, 0, 0);
        }
    }

    // ---- hoist epilogue operands (h==0 only) under the barrier wait ----
    float wtmp[4][8];
    float4 bo4[4];
    float mk = 0.f;
    if (h == 0) {
        #pragma unroll
        for (int t = 0; t < 4; ++t) {
            *(float4*)&wtmp[t][0] = *(const float4*)(Wo + (size_t)(t * 16 + lo) * C + quad * 8);
            *(float4*)&wtmp[t][4] = *(const float4*)(Wo + (size_t)(t * 16 + lo) * C + quad * 8 + 4);
            bo4[t] = *(const float4*)(bo + t * 16 + quad * 4);
        }
        mk = mask[myq];
    }

    // ---- merge wave1 partials into wave0 ----
    if (h == 1) {
        #pragma unroll
        for (int r = 0; r < 4; ++r) {
            mrg[lane * 9 + r]     = O0[r];
            mrg[lane * 9 + 4 + r] = O1[r];
        }
        mrg[lane * 9 + 8] = psum;
    }
    __syncthreads();
    if (h == 1) return;

    #pragma unroll
    for (int r = 0; r < 4; ++r) {
        O0[r] += mrg[lane * 9 + r];
        O1[r] += mrg[lane * 9 + 4 + r];
    }
    psum += mrg[lane * 9 + 8];

    // ---- denominator across quads for each query col ----
    float dsum = psum;
    dsum += __shfl_xor(dsum, 16);
    dsum += __shfl_xor(dsum, 32);
    const float inv = 1.f / dsum;

    // ---- epilogue: T = relu(O^T*inv) -> B-layout via quad-permute ----
    unsigned tw[2][2];
    tw[0][0] = pk2(fmaxf(O0[0] * inv, 0.f), fmaxf(O0[1] * inv, 0.f));
    tw[0][1] = pk2(fmaxf(O0[2] * inv, 0.f), fmaxf(O0[3] * inv, 0.f));
    tw[1][0] = pk2(fmaxf(O1[0] * inv, 0.f), fmaxf(O1[1] * inv, 0.f));
    tw[1][1] = pk2(fmaxf(O1[2] * inv, 0.f), fmaxf(O1[3] * inv, 0.f));

    union { int i[4]; bf16x8 v; } tb;
    #pragma unroll
    for (int i = 0; i < 4; ++i) {
        const int src = qsl + 16 * (i >> 1);
        const int v0 = __shfl((int)tw[0][i & 1], src);
        const int v1 = __shfl((int)tw[1][i & 1], src);
        tb.i[i] = (quad < 2) ? v0 : v1;
    }

    #pragma unroll
    for (int t = 0; t < 4; ++t) {
        union { unsigned u[4]; bf16x8 v; } wo;
        #pragma unroll
        for (int i = 0; i < 4; ++i) wo.u[i] = pk2(wtmp[t][2 * i], wtmp[t][2 * i + 1]);
        const f32x4 R = __builtin_amdgcn_mfma_f32_16x16x32_bf16(wo.v, tb.v, zero, 0, 0, 0);
        const float* bop = (const float*)&bo4[t];
        #pragma unroll
        for (int r = 0; r < 4; ++r)
            out[(size_t)(t * 16 + quad * 4 + r) * L + myq] = (R[r] + bop[r]) * mk;
    }
}

extern "C" void kernel_launch(void* const* d_in, const int* in_sizes, int n_in,
                              void* d_out, int out_size, void* d_ws, size_t ws_size,
                              hipStream_t stream)
{
    const float* x1   = (const float*)d_in[0];
    // d_in[1] = x2 : unused (encoder stage)
    const float* mask = (const float*)d_in[2];
    const float* Wq   = (const float*)d_in[3];
    const float* bq   = (const float*)d_in[4];
    const float* Wk   = (const float*)d_in[5];
    const float* bk   = (const float*)d_in[6];
    const float* Wv   = (const float*)d_in[7];
    const float* bv   = (const float*)d_in[8];
    const float* Wo   = (const float*)d_in[9];
    const float* bo   = (const float*)d_in[10];
    float* out = (float*)d_out;

    const int L = in_sizes[0] / QD;                  // 65536
    unsigned short* qT = (unsigned short*)d_ws;      // L*32 bf16
    unsigned short* kT = qT + (size_t)L * C;         // L*32 bf16
    unsigned short* v2 = kT + (size_t)L * C;         // L*32 bf16 (tiled)

    // MFMA qkv: 64 timesteps per wg (4 waves x 16) -> L/64 = 1024 wgs
    hipLaunchKernelGGL(qkv_proj, dim3(L / 64), dim3(256), 0, stream,
                       x1, Wq, bq, Wk, bk, Wv, bv, qT, kT, v2, L);

    // one wg per 16-query tile: L/16 = 4096 wgs (2 waves each, split-K)
    hipLaunchKernelGGL(att_kernel, dim3(L / 16), dim3(128), 0, stream,
                       qT, kT, v2, mask, Wo, bo, out, L);
}

// Round 8
// 123.931 us; speedup vs baseline: 1.0771x; 1.0771x over previous
//
#include <hip/hip_runtime.h>
#include <hip/hip_bf16.h>
#include <math.h>

#define C    32      // attention dim
#define QD   64      // x1 channels
#define VD   64      // output channels
#define BLK  512     // sliding window block length
#define HALF 256

typedef __attribute__((ext_vector_type(8))) short bf16x8;
typedef __attribute__((ext_vector_type(4))) float f32x4;

static __device__ inline unsigned short f2bf(float x) {
    union { float f; unsigned u; } v; v.f = x;
    unsigned r = v.u + 0x7FFFu + ((v.u >> 16) & 1u);   // RNE
    return (unsigned short)(r >> 16);
}

// pack 2 floats -> one dword holding 2 bf16 (low = a, high = b)
static __device__ inline unsigned pk2(float a, float b) {
    union { __hip_bfloat162 h; unsigned u; } x;
    x.h = __float22bfloat162_rn(make_float2(a, b));
    return x.u;
}

// ---------------- kernel 1: QKV projection via MFMA + LDS-staged stores ----
// qkv history: R1 fused-96-acc spill (VGPR cap 60); R3 runtime-kind loop
// broke SROA (VGPR 32, scratch); R5 MFMA rewrite 38->23us; R6 LDS-staged
// coalesced stores NEUTRAL -> qkv is NOT store/VALU/HBM-bound; parked.
// Layouts for att_kernel:
//   qT bf16 (L,32) pre-scaled; kT bf16 (L,32);
//   v2 bf16 tiled: idx = ((l>>6)<<11) + (((l>>5)&1)<<10) + ch*32 + (l&31)
__global__ __launch_bounds__(256) void qkv_proj(
    const float* __restrict__ x1,
    const float* __restrict__ Wq, const float* __restrict__ bq,
    const float* __restrict__ Wk, const float* __restrict__ bk,
    const float* __restrict__ Wv, const float* __restrict__ bv,
    unsigned short* __restrict__ qT, unsigned short* __restrict__ kT,
    unsigned short* __restrict__ v2, int L)
{
    __shared__ uint4 lq[256], lk[256], lv[256];   // 3 x 4KB

    const int lane = threadIdx.x & 63;
    const int wv   = threadIdx.x >> 6;
    const int lo   = lane & 15;
    const int quad = lane >> 4;

    const int tile = blockIdx.x * 4 + wv;   // one 16-l tile per wave
    const int l    = tile * 16 + lo;
    const int ll   = wv * 16 + lo;          // l offset within the wg's 64-l block

    float xv[16];
    #pragma unroll
    for (int kc = 0; kc < 2; ++kc)
        #pragma unroll
        for (int j = 0; j < 8; ++j)
            xv[kc * 8 + j] = x1[(size_t)(kc * 32 + quad * 8 + j) * L + l];

    bf16x8 B[2];
    #pragma unroll
    for (int kc = 0; kc < 2; ++kc) {
        union { unsigned u[4]; bf16x8 v; } bb;
        #pragma unroll
        for (int p = 0; p < 4; ++p)
            bb.u[p] = pk2(xv[kc * 8 + 2 * p], xv[kc * 8 + 2 * p + 1]);
        B[kc] = bb.v;
    }

    bf16x8 A[3][2][2];  // [kind][otile][kchunk] — static indices after unroll
    #pragma unroll
    for (int kind = 0; kind < 3; ++kind) {
        const float* __restrict__ Wp = (kind == 0) ? Wq : ((kind == 1) ? Wk : Wv);
        const float sc = (kind == 0) ? 0.17677669529663689f : 1.0f;
        #pragma unroll
        for (int ot = 0; ot < 2; ++ot) {
            #pragma unroll
            for (int kc = 0; kc < 2; ++kc) {
                const float* wp = Wp + (size_t)(ot * 16 + lo) * QD + kc * 32 + quad * 8;
                const float4 w0 = *(const float4*)wp;
                const float4 w1 = *(const float4*)(wp + 4);
                union { unsigned u[4]; bf16x8 v; } t;
                t.u[0] = pk2(w0.x * sc, w0.y * sc);
                t.u[1] = pk2(w0.z * sc, w0.w * sc);
                t.u[2] = pk2(w1.x * sc, w1.y * sc);
                t.u[3] = pk2(w1.z * sc, w1.w * sc);
                A[kind][ot][kc] = t.v;
            }
        }
    }

    const f32x4 zero = {0.f, 0.f, 0.f, 0.f};
    f32x4 acc[3][2];
    #pragma unroll
    for (int kind = 0; kind < 3; ++kind)
        #pragma unroll
        for (int ot = 0; ot < 2; ++ot) {
            f32x4 a = __builtin_amdgcn_mfma_f32_16x16x32_bf16(A[kind][ot][0], B[0], zero, 0, 0, 0);
            acc[kind][ot] = __builtin_amdgcn_mfma_f32_16x16x32_bf16(A[kind][ot][1], B[1], a, 0, 0, 0);
        }

    #pragma unroll
    for (int kind = 0; kind < 2; ++kind) {
        const float* __restrict__ bp = (kind == 0) ? bq : bk;
        const float sc = (kind == 0) ? 0.17677669529663689f : 1.0f;
        unsigned* __restrict__ ld = (unsigned*)((kind == 0) ? lq : lk);
        #pragma unroll
        for (int ot = 0; ot < 2; ++ot) {
            const float4 b4 = *(const float4*)(bp + ot * 16 + quad * 4);
            const float r0 = acc[kind][ot][0] + b4.x * sc;
            const float r1 = acc[kind][ot][1] + b4.y * sc;
            const float r2 = acc[kind][ot][2] + b4.z * sc;
            const float r3 = acc[kind][ot][3] + b4.w * sc;
            ld[ll * 16 + ot * 8 + quad * 2 + 0] = pk2(r0, r1);
            ld[ll * 16 + ot * 8 + quad * 2 + 1] = pk2(r2, r3);
        }
    }
    {
        unsigned short* __restrict__ lvs = (unsigned short*)lv;
        const int vb = ((ll >> 5) << 10) + (ll & 31);
        #pragma unroll
        for (int ot = 0; ot < 2; ++ot) {
            const float4 b4 = *(const float4*)(bv + ot * 16 + quad * 4);
            const float* bp4 = (const float*)&b4;
            #pragma unroll
            for (int r = 0; r < 4; ++r)
                lvs[vb + (ot * 16 + quad * 4 + r) * 32] = f2bf(acc[2][ot][r] + bp4[r]);
        }
    }

    __syncthreads();

    const int t = threadIdx.x;
    const size_t blk16 = (size_t)blockIdx.x * 256;
    ((uint4*)qT)[blk16 + t] = lq[t];
    ((uint4*)kT)[blk16 + t] = lk[t];
    ((uint4*)v2)[blk16 + t] = lv[t];
}

// ---------------- kernel 2: MFMA flash attention, LDS-shared window ------
// R8 restructure: one wg = 4 waves = 64 queries (4 adjacent 16-query tiles
// of the SAME 512-block -> same kstart). Each 64-key chunk staged ONCE per
// wg into LDS (K 4KB + V 4KB, double-buffered = 16KB), T14 issue-early /
// write-late, ONE barrier per chunk. K/V L2 traffic /4.7 (268->57 MB).
// Split-K + merge dropped: each wave walks its own full window (n differs
// by <=1 chunk across the wg; idle waves still stage+barrier).
// LDS swizzle: rows are 64B -> column bits are 4-5 only; XOR with
// ((row>>1)&3)<<4 (write: row=t>>2 -> ((t>>3)&3); read: ((lo>>1)&3),
// invariant across t/g since those add multiples of 8 to the row).
// Analysis: both write and read land 2 lanes/bank = free (m136).
// (row&7)<<4 from G4 would toggle bit 6 = a ROW bit -> corruption.
// LPT + XCD affinity: id = (7-sub)*128 + w -> long wgs first, id%8 == w%8.
// R7 per-wave register pipeline was neutral->negative: dropped.
__global__ __launch_bounds__(256, 4) void att_kernel(
    const unsigned short* __restrict__ qT,
    const unsigned short* __restrict__ kT,
    const unsigned short* __restrict__ v2,
    const float* __restrict__ mask,
    const float* __restrict__ Wo, const float* __restrict__ bo,
    float* __restrict__ out, int L)
{
    __shared__ unsigned short sK[2][2048];   // [buf][64 keys][32 ch]
    __shared__ unsigned short sV[2][2048];   // [buf][2][32 ch][32 keys]

    const int tid  = threadIdx.x;
    const int lane = tid & 63;
    const int wv   = tid >> 6;          // wave 0..3 -> tile s = sub*4+wv
    const int lo   = lane & 15;
    const int quad = lane >> 4;

    const int id  = blockIdx.x;
    const int w   = id & 127;           // 512-block index
    const int sub = 7 - (id >> 7);      // 64-query group within block (LPT)
    const int s   = sub * 4 + wv;
    const int wq0 = w * BLK + s * 16;

    const int kstart = max(0, w * BLK - HALF);
    const int nwv  = ((wq0 + 15 - kstart) >> 6) + 1;                      // my chunks
    const int nmax = ((w * BLK + (sub * 4 + 3) * 16 + 15 - kstart) >> 6) + 1; // wg chunks
    const int myq  = wq0 + lo;

    // Q B-frag: B[k=c][n=q]
    const bf16x8 qB = *(const bf16x8*)(qT + (size_t)myq * C + quad * 8);

    const f32x4 zero = {0.f, 0.f, 0.f, 0.f};
    f32x4 O0 = zero, O1 = zero;
    float psum = 0.f;

    const int qsl = lo + 16 * ((quad & 1) << 1);

    // swizzled LDS byte offsets
    const int wrOff = (tid * 16) ^ (((tid >> 3) & 3) << 4);      // ds_write_b128
    const int rdX   = (quad << 4) ^ (((lo >> 1) & 3) << 4);      // read column

    // ---- prologue: stage chunk 0 ----
    {
        const uint4 gk = ((const uint4*)(kT + (size_t)kstart * C))[tid];
        const uint4 gv = ((const uint4*)(v2 + ((size_t)(kstart >> 6) << 11)))[tid];
        *(uint4*)((char*)sK[0] + wrOff) = gk;
        *(uint4*)((char*)sV[0] + wrOff) = gv;
    }
    __syncthreads();

    for (int j = 0; j < nmax; ++j) {
        const int kb  = kstart + (j << 6);
        const int cur = j & 1;
        const bool more = (j + 1) < nmax;

        // issue next chunk's global loads EARLY (latency hidden by compute)
        uint4 gk, gv;
        if (more) {
            const int kb1 = kb + 64;
            gk = ((const uint4*)(kT + (size_t)kb1 * C))[tid];
            gv = ((const uint4*)(v2 + ((size_t)(kb1 >> 6) << 11)))[tid];
        }

        if (j < nwv) {
            // ---- S = K.Q^T from LDS ----
            f32x4 S[4];
            float4 fm4[4];
            const char* kbuf = (const char*)sK[cur];
            #pragma unroll
            for (int t = 0; t < 4; ++t) {
                const bf16x8 kA = *(const bf16x8*)(kbuf + ((t * 16 + lo) * 64 + rdX));
                S[t] = __builtin_amdgcn_mfma_f32_16x16x32_bf16(kA, qB, zero, 0, 0, 0);
                fm4[t] = *(const float4*)(mask + kb + t * 16 + quad * 4);
            }

            unsigned wp[4][2];
            if (j == nwv - 1) {
                // causal chunk
                #pragma unroll
                for (int t = 0; t < 4; ++t) {
                    const float* fmp = (const float*)&fm4[t];
                    float p[4];
                    #pragma unroll
                    for (int r = 0; r < 4; ++r) {
                        const int key = kb + t * 16 + quad * 4 + r;
                        const float pd = (key <= myq) ? __expf(S[t][r]) * (fmp[r] + 1e-9f) : 0.f;
                        psum += pd;
                        p[r] = pd * fmp[r];
                    }
                    wp[t][0] = pk2(p[0], p[1]);
                    wp[t][1] = pk2(p[2], p[3]);
                }
            } else {
                #pragma unroll
                for (int t = 0; t < 4; ++t) {
                    const float* fmp = (const float*)&fm4[t];
                    float p[4];
                    #pragma unroll
                    for (int r = 0; r < 4; ++r) {
                        const float pd = __expf(S[t][r]) * (fmp[r] + 1e-9f);
                        psum += pd;
                        p[r] = pd * fmp[r];
                    }
                    wp[t][0] = pk2(p[0], p[1]);
                    wp[t][1] = pk2(p[2], p[3]);
                }
            }

            // ---- PV from LDS ----
            const char* vbuf = (const char*)sV[cur];
            #pragma unroll
            for (int g = 0; g < 2; ++g) {
                union { int i[4]; bf16x8 v; } pb;
                #pragma unroll
                for (int i = 0; i < 4; ++i) {
                    const int src = qsl + 16 * (i >> 1);
                    const int v0 = __shfl((int)wp[2 * g][i & 1], src);
                    const int v1 = __shfl((int)wp[2 * g + 1][i & 1], src);
                    pb.i[i] = (quad < 2) ? v0 : v1;
                }
                const bf16x8 vA0 = *(const bf16x8*)(vbuf + (g * 2048 + lo * 64 + rdX));
                const bf16x8 vA1 = *(const bf16x8*)(vbuf + (g * 2048 + (16 + lo) * 64 + rdX));
                O0 = __builtin_amdgcn_mfma_f32_16x16x32_bf16(vA0, pb.v, O0, 0, 0, 0);
                O1 = __builtin_amdgcn_mfma_f32_16x16x32_bf16(vA1, pb.v, O1, 0, 0, 0);
            }
        }

        // write next chunk into the other buffer, then one barrier
        if (more) {
            *(uint4*)((char*)sK[cur ^ 1] + wrOff) = gk;
            *(uint4*)((char*)sV[cur ^ 1] + wrOff) = gv;
        }
        __syncthreads();
    }

    // ---- denominator across quads for each query col ----
    float dsum = psum;
    dsum += __shfl_xor(dsum, 16);
    dsum += __shfl_xor(dsum, 32);
    const float inv = 1.f / dsum;

    // ---- epilogue: T = relu(O^T*inv) -> B-layout via quad-permute ----
    unsigned tw[2][2];
    tw[0][0] = pk2(fmaxf(O0[0] * inv, 0.f), fmaxf(O0[1] * inv, 0.f));
    tw[0][1] = pk2(fmaxf(O0[2] * inv, 0.f), fmaxf(O0[3] * inv, 0.f));
    tw[1][0] = pk2(fmaxf(O1[0] * inv, 0.f), fmaxf(O1[1] * inv, 0.f));
    tw[1][1] = pk2(fmaxf(O1[2] * inv, 0.f), fmaxf(O1[3] * inv, 0.f));

    union { int i[4]; bf16x8 v; } tb;
    #pragma unroll
    for (int i = 0; i < 4; ++i) {
        const int src = qsl + 16 * (i >> 1);
        const int v0 = __shfl((int)tw[0][i & 1], src);
        const int v1 = __shfl((int)tw[1][i & 1], src);
        tb.i[i] = (quad < 2) ? v0 : v1;
    }

    const float mk = mask[myq];
    #pragma unroll
    for (int t = 0; t < 4; ++t) {
        float wtmp[8];
        *(float4*)&wtmp[0] = *(const float4*)(Wo + (size_t)(t * 16 + lo) * C + quad * 8);
        *(float4*)&wtmp[4] = *(const float4*)(Wo + (size_t)(t * 16 + lo) * C + quad * 8 + 4);
        union { unsigned u[4]; bf16x8 v; } wo;
        #pragma unroll
        for (int i = 0; i < 4; ++i) wo.u[i] = pk2(wtmp[2 * i], wtmp[2 * i + 1]);
        const f32x4 R = __builtin_amdgcn_mfma_f32_16x16x32_bf16(wo.v, tb.v, zero, 0, 0, 0);
        const float4 bo4 = *(const float4*)(bo + t * 16 + quad * 4);
        const float* bop = (const float*)&bo4;
        #pragma unroll
        for (int r = 0; r < 4; ++r)
            out[(size_t)(t * 16 + quad * 4 + r) * L + myq] = (R[r] + bop[r]) * mk;
    }
}

extern "C" void kernel_launch(void* const* d_in, const int* in_sizes, int n_in,
                              void* d_out, int out_size, void* d_ws, size_t ws_size,
                              hipStream_t stream)
{
    const float* x1   = (const float*)d_in[0];
    // d_in[1] = x2 : unused (encoder stage)
    const float* mask = (const float*)d_in[2];
    const float* Wq   = (const float*)d_in[3];
    const float* bq   = (const float*)d_in[4];
    const float* Wk   = (const float*)d_in[5];
    const float* bk   = (const float*)d_in[6];
    const float* Wv   = (const float*)d_in[7];
    const float* bv   = (const float*)d_in[8];
    const float* Wo   = (const float*)d_in[9];
    const float* bo   = (const float*)d_in[10];
    float* out = (float*)d_out;

    const int L = in_sizes[0] / QD;                  // 65536
    unsigned short* qT = (unsigned short*)d_ws;      // L*32 bf16
    unsigned short* kT = qT + (size_t)L * C;         // L*32 bf16
    unsigned short* v2 = kT + (size_t)L * C;         // L*32 bf16 (tiled)

    // MFMA qkv: 64 timesteps per wg (4 waves x 16) -> L/64 = 1024 wgs
    hipLaunchKernelGGL(qkv_proj, dim3(L / 64), dim3(256), 0, stream,
                       x1, Wq, bq, Wk, bk, Wv, bv, qT, kT, v2, L);

    // one wg per 64-query group: L/64 = 1024 wgs (4 waves, shared window)
    hipLaunchKernelGGL(att_kernel, dim3(L / 64), dim3(256), 0, stream,
                       qT, kT, v2, mask, Wo, bo, out, L);
}